// Round 14
// baseline (94.877 us; speedup 1.0000x reference)
//
#include <hip/hip_runtime.h>
#include <math.h>

#define NSV 512

__device__ __forceinline__ float2 gload2(const float* p) {
    unsigned long long u = __hip_atomic_load((const unsigned long long*)p,
                            __ATOMIC_RELAXED, __HIP_MEMORY_SCOPE_AGENT);
    union { unsigned long long u; float2 f; } c; c.u = u; return c.f;
}

// ---------------------------------------------------------------------------
// K1 role A (blocks 0..255): pchain split by spin-half (proven R11/R12).
// ---------------------------------------------------------------------------
__device__ void pchain_role(int b, const float* __restrict__ r,
                            const float* __restrict__ apos,
                            const float* __restrict__ W0w, const float* __restrict__ W0b,
                            const float* __restrict__ W1w, const float* __restrict__ W1b,
                            const float* __restrict__ W2w, const float* __restrict__ W2b,
                            float* __restrict__ expv,
                            float* __restrict__ pme1, float* __restrict__ pme2,
                            float* __restrict__ pme3, float* sh)
{
    float* rL    = sh;           // 384
    float* W0l   = sh + 384;     // 256
    float* aposL = sh + 640;     // 96
    float* shex  = sh + 736;     // 32
    float* p0c   = sh + 768;     // 64*4
    float* PA    = sh + 1024;    // 64*68 = 4352
    float* Wbuf  = sh + 5376;    // 4096
    const int j  = b >> 1, sp = b & 1;
    const int t  = threadIdx.x;
    const int i  = t >> 3;          // local row 0..63
    const int o0 = (t & 7) * 8;     // 8 outputs per thread

    if (t < 384) rL[t] = r[t];
    else if (t < 480) aposL[t - 384] = apos[t - 384];
    for (int idx = t; idx < 4096; idx += 512) Wbuf[idx] = W1w[idx];
    if (t < 256) W0l[t] = W0w[t];
    __syncthreads();

    const float rjx = rL[j*3+0], rjy = rL[j*3+1], rjz = rL[j*3+2];
    if (t < 64) {        // p0 rows sp*64+t of column j
        const int ii = sp*64 + t;
        float dx = rjx - rL[ii*3+0], dy = rjy - rL[ii*3+1], dz = rjz - rL[ii*3+2];
        float len = (ii == j) ? 0.f : sqrtf(dx*dx + dy*dy + dz*dz);
        p0c[t*4+0]=dx; p0c[t*4+1]=dy; p0c[t*4+2]=dz; p0c[t*4+3]=len;
    } else if (sp == 0 && t < 96) {   // exp terms for expv[j]
        const int k = t - 64;
        float dx = rjx - aposL[k*3+0], dy = rjy - aposL[k*3+1], dz = rjz - aposL[k*3+2];
        shex[k] = expf(-sqrtf(dx*dx + dy*dy + dz*dz));
    }
    __syncthreads();

    {   // layer0: PA[i][o] = tanh(p0c[i] @ W0 + b0), 8 outputs/thread
        const float x0=p0c[i*4+0], x1=p0c[i*4+1], x2=p0c[i*4+2], x3=p0c[i*4+3];
        #pragma unroll
        for (int k = 0; k < 8; ++k) {
            const int o = o0 + k;
            float a = W0b[o];
            a = fmaf(x0, W0l[o],     a);
            a = fmaf(x1, W0l[64+o],  a);
            a = fmaf(x2, W0l[128+o], a);
            a = fmaf(x3, W0l[192+o], a);
            PA[i*68+o] = tanhf(a);
        }
    }
    if (sp == 0 && t == 4) {
        float s = 0.f;
        #pragma unroll 8
        for (int k = 0; k < 32; ++k) s += shex[k];
        expv[j] = s;
    }
    __syncthreads();

    // pme1 spin-half + layer1 (W1, +res)
    if (t < 64) {
        float s = 0.f;
        #pragma unroll 8
        for (int k = 0; k < 64; ++k) s += PA[k*68 + t];
        pme1[j*128 + sp*64 + t] = s * 0.015625f;
    }
    float acc[8], res[8];
    const float* pa = PA + i*68;
    {
        #pragma unroll
        for (int k = 0; k < 8; ++k) acc[k] = W1b[o0+k];
        #pragma unroll 4
        for (int c = 0; c < 64; ++c) {
            const float av = pa[c];
            const float* wr = Wbuf + c*64 + o0;
            float4 wa = *reinterpret_cast<const float4*>(wr);
            float4 wb = *reinterpret_cast<const float4*>(wr+4);
            acc[0]=fmaf(av,wa.x,acc[0]); acc[1]=fmaf(av,wa.y,acc[1]);
            acc[2]=fmaf(av,wa.z,acc[2]); acc[3]=fmaf(av,wa.w,acc[3]);
            acc[4]=fmaf(av,wb.x,acc[4]); acc[5]=fmaf(av,wb.y,acc[5]);
            acc[6]=fmaf(av,wb.z,acc[6]); acc[7]=fmaf(av,wb.w,acc[7]);
        }
        #pragma unroll
        for (int k = 0; k < 8; ++k) res[k] = pa[o0+k];
    }
    __syncthreads();
    #pragma unroll
    for (int k = 0; k < 8; ++k) PA[i*68+o0+k] = tanhf(acc[k]) + res[k];
    __syncthreads();

    // pme2 spin-half + restage Wbuf = W2
    if (t < 64) {
        float s = 0.f;
        #pragma unroll 8
        for (int k = 0; k < 64; ++k) s += PA[k*68 + t];
        pme2[j*128 + sp*64 + t] = s * 0.015625f;
    }
    for (int idx = t; idx < 4096; idx += 512) Wbuf[idx] = W2w[idx];
    __syncthreads();

    {   // layer2 (W2, +res)
        #pragma unroll
        for (int k = 0; k < 8; ++k) acc[k] = W2b[o0+k];
        #pragma unroll 4
        for (int c = 0; c < 64; ++c) {
            const float av = pa[c];
            const float* wr = Wbuf + c*64 + o0;
            float4 wa = *reinterpret_cast<const float4*>(wr);
            float4 wb = *reinterpret_cast<const float4*>(wr+4);
            acc[0]=fmaf(av,wa.x,acc[0]); acc[1]=fmaf(av,wa.y,acc[1]);
            acc[2]=fmaf(av,wa.z,acc[2]); acc[3]=fmaf(av,wa.w,acc[3]);
            acc[4]=fmaf(av,wb.x,acc[4]); acc[5]=fmaf(av,wb.y,acc[5]);
            acc[6]=fmaf(av,wb.z,acc[6]); acc[7]=fmaf(av,wb.w,acc[7]);
        }
        #pragma unroll
        for (int k = 0; k < 8; ++k) res[k] = pa[o0+k];
    }
    __syncthreads();
    #pragma unroll
    for (int k = 0; k < 8; ++k) PA[i*68+o0+k] = tanhf(acc[k]) + res[k];
    __syncthreads();

    if (t < 64) {        // pme3 spin-half
        float s = 0.f;
        #pragma unroll 8
        for (int k = 0; k < 64; ++k) s += PA[k*68 + t];
        pme3[j*128 + sp*64 + t] = s * 0.015625f;
    }
}

// ---------------------------------------------------------------------------
// K1 role B (blocks 256..511): layer-0 s-GEMM, geometry-sourced (R12-proven).
// ---------------------------------------------------------------------------
__device__ void a0_role(int ab, const float* __restrict__ r,
                        const float* __restrict__ apos,
                        const float* __restrict__ V0w, const float* __restrict__ V0b,
                        float* __restrict__ svA, float* __restrict__ psA, float* sh)
{
    constexpr int KP = 136, KP2 = 68;
    float* As    = sh;           // 544
    float* smL   = sh + 544;     // 256
    float* red   = sh + 800;     // 512
    float* t1L   = sh + 1312;    // 64
    float* rL    = sh + 1376;    // 384
    float* aposL = sh + 1760;    // 96
    const int t  = threadIdx.x;
    const int et = ab >> 3, e0 = et * 4;
    const int o0 = (ab & 7) * 64;
    const int ol = t & 63, o = o0 + ol;
    const int wv = t >> 6;

    if (t < 384) rL[t] = r[t];
    else if (t < 480) aposL[t - 384] = apos[t - 384];
    __syncthreads();

    if (t < 128) {       // As sv-part: 4 electrons x 32 atoms
        const int e_l = t >> 5, k = t & 31;
        const int e = e0 + e_l;
        float dx = rL[e*3+0]-aposL[k*3+0], dy = rL[e*3+1]-aposL[k*3+1],
              dz = rL[e*3+2]-aposL[k*3+2];
        float len = sqrtf(dx*dx + dy*dy + dz*dz);
        float* dst = As + e_l*KP + 8 + k*4;
        dst[0]=dx; dst[1]=dy; dst[2]=dz; dst[3]=len;
    } else if (t < 160) { // As pme0-part: 4 electrons x 8 feats
        const int q = t - 128;
        const int e_l = q >> 3, outp = q & 7;
        const int spin = outp >> 2, c = outp & 3;
        const int e = e0 + e_l;
        const float ex = rL[e*3+0], ey = rL[e*3+1], ez = rL[e*3+2];
        float s = 0.f;
        for (int i2 = 0; i2 < 64; ++i2) {
            const int ii = spin*64 + i2;
            float dx = ex - rL[ii*3+0], dy = ey - rL[ii*3+1], dz = ez - rL[ii*3+2];
            float v = (c==0)?dx:(c==1)?dy:(c==2)?dz:
                      ((ii==e)?0.f:sqrtf(dx*dx+dy*dy+dz*dz));
            s += v;
        }
        As[e_l*KP + outp] = s * 0.015625f;
    }
    {   // smean0 from geometry: two half-sums per thread
        const int outp = t >> 1, half = t & 1;
        const int spin = outp >> 7, cc = outp & 127, a_i = cc >> 2, d = cc & 3;
        const float ax = aposL[a_i*3+0], ay = aposL[a_i*3+1], az = aposL[a_i*3+2];
        float s = 0.f;
        #pragma unroll 8
        for (int q = 0; q < 32; ++q) {
            const int e = spin*64 + half*32 + q;
            float dx = rL[e*3+0]-ax, dy = rL[e*3+1]-ay, dz = rL[e*3+2]-az;
            float len = sqrtf(dx*dx + dy*dy + dz*dz);
            s += (d==0)?dx:(d==1)?dy:(d==2)?dz:len;
        }
        red[t] = s;
    }
    __syncthreads();
    if (t < 256) smL[t] = (red[2*t] + red[2*t+1]) * 0.015625f;
    __syncthreads();

    {   // t1 partials over 8 waves
        float a1 = 0.f;
        const float* Wp = V0w + (size_t)(wv*32)*NSV + o;
        const float* mp = smL + wv*32;
        #pragma unroll 8
        for (int k = 0; k < 32; ++k) a1 = fmaf(mp[k], Wp[(size_t)k*NSV], a1);
        red[wv*64 + ol] = a1;
    }
    __syncthreads();
    if (t < 64) {
        float s = V0b[o0 + t];
        #pragma unroll
        for (int g = 0; g < 8; ++g) s += red[g*64 + t];
        t1L[t] = s;
    }
    __syncthreads();

    const int e_l = wv & 3, kh = wv >> 2;
    {
        float a2 = (kh == 0) ? t1L[ol] : 0.f;
        const float* Ap = As + e_l*KP + kh*KP2;
        const float* Wp = V0w + (size_t)(256 + kh*KP2)*NSV + o;
        #pragma unroll 16
        for (int k = 0; k < KP2; ++k)
            a2 = fmaf(Ap[k], Wp[(size_t)k*NSV], a2);
        red[wv*64 + ol] = a2;
    }
    __syncthreads();
    float v = 0.f;
    if (t < 256) {
        v = tanhf(red[(t>>6)*64 + (t&63)] + red[((t>>6)+4)*64 + (t&63)]);
        svA[(size_t)(e0 + (t>>6))*NSV + o0 + (t&63)] = v;
    }
    __syncthreads();
    if (t < 256) red[t] = v;
    __syncthreads();
    if (t < 64) {
        float s = red[t] + red[64+t] + red[128+t] + red[192+t];
        psA[(size_t)et*NSV + o0 + t] = s;
    }
}

// ---------------------------------------------------------------------------
// K1 role C (blocks 512..575): C = vh @ wu (512x64 per spin), LDS-chunked.
// ---------------------------------------------------------------------------
__device__ void headc_role(int g, const float* __restrict__ vh,
                           const float* __restrict__ wu,
                           float* __restrict__ Cdst, float* sh)
{
    float* wuL = sh;          // 4096
    float* vhL = sh + 4096;   // 1024
    const int t = threadIdx.x;
    const int o2 = t & 63, wq = t >> 6;      // wq 0..7
    const int f0 = g * 16;
    float a0 = 0.f, a1 = 0.f;
    for (int hc = 0; hc < 4; ++hc) {
        __syncthreads();
        for (int idx = t; idx < 4096; idx += 512)
            wuL[idx] = wu[(size_t)(hc*64 + (idx>>6))*64 + (idx&63)];
        for (int idx = t; idx < 1024; idx += 512)
            vhL[idx] = vh[(size_t)(f0 + (idx>>6))*256 + hc*64 + (idx&63)];
        __syncthreads();
        #pragma unroll 8
        for (int h = 0; h < 64; ++h) {
            const float wuv = wuL[h*64 + o2];
            a0 = fmaf(vhL[wq*64 + h],     wuv, a0);
            a1 = fmaf(vhL[(wq+8)*64 + h], wuv, a1);
        }
    }
    Cdst[(size_t)(f0 + wq)*64 + o2]     = a0;
    Cdst[(size_t)(f0 + wq + 8)*64 + o2] = a1;
}

// K1 role D (blocks 576..577): cb = vhb @ wu + wub  (64 per spin).
__device__ void cb_role(const float* __restrict__ vhb, const float* __restrict__ wu,
                        const float* __restrict__ wub, float* __restrict__ cbdst,
                        float* sh)
{
    const int t = threadIdx.x;
    const int o2 = t & 63, wq = t >> 6;
    float acc = 0.f;
    #pragma unroll
    for (int k = 0; k < 32; ++k) {
        const int h = wq*32 + k;
        acc = fmaf(vhb[h], wu[(size_t)h*64 + o2], acc);
    }
    sh[t] = acc;
    __syncthreads();
    if (t < 64) {
        float s = wub[t];
        #pragma unroll
        for (int g = 0; g < 8; ++g) s += sh[g*64 + t];
        cbdst[t] = s;
    }
}

// ---------------------------------------------------------------------------
// K1: pchain(256) || A0(256) || headC(64) || cb(2) — all independent roles.
// ---------------------------------------------------------------------------
__global__ __launch_bounds__(512)
void front_kernel(const float* __restrict__ r, const float* __restrict__ apos,
                  const float* __restrict__ V0w, const float* __restrict__ V0b,
                  const float* __restrict__ W0w, const float* __restrict__ W0b,
                  const float* __restrict__ W1w, const float* __restrict__ W1b,
                  const float* __restrict__ W2w, const float* __restrict__ W2b,
                  const float* __restrict__ vhuw, const float* __restrict__ vhub,
                  const float* __restrict__ vhdw, const float* __restrict__ vhdb,
                  const float* __restrict__ wuw,  const float* __restrict__ wub,
                  const float* __restrict__ wdw,  const float* __restrict__ wdb,
                  float* __restrict__ svA, float* __restrict__ expv,
                  float* __restrict__ pme1, float* __restrict__ pme2,
                  float* __restrict__ pme3, float* __restrict__ psA,
                  float* __restrict__ Cmat, float* __restrict__ cb)
{
    __shared__ __align__(16) float sh[9472];
    const int b = blockIdx.x;
    if (b < 256) {
        pchain_role(b, r, apos, W0w, W0b, W1w, W1b, W2w, W2b,
                    expv, pme1, pme2, pme3, sh);
    } else if (b < 512) {
        a0_role(b - 256, r, apos, V0w, V0b, svA, psA, sh);
    } else if (b < 576) {
        const int g = b - 512;
        const int spin = g >> 5;
        headc_role(g & 31, spin ? vhdw : vhuw, spin ? wdw : wuw,
                   Cmat + (size_t)spin*32768, sh);
    } else {
        const int spin = b - 576;
        cb_role(spin ? vhdb : vhub, spin ? wdw : wuw, spin ? wdb : wub,
                cb + spin*64, sh);
    }
}

// ---------------------------------------------------------------------------
// A kernel (layers 1,2). Grid 256 (+1 for K2: block 256 initializes
// orb = cb broadcast and resets the last-block counter).
// ---------------------------------------------------------------------------
template<int FS, int FP>
__global__ __launch_bounds__(512)
void a2_kernel(const float* __restrict__ svIn, const float* __restrict__ pmeIn,
               const float* __restrict__ psumIn,
               const float* __restrict__ Vw, const float* __restrict__ Vb,
               float* __restrict__ svOut, float* __restrict__ psumOut,
               float* __restrict__ orbInit, const float* __restrict__ cb,
               unsigned* __restrict__ cnt)
{
    constexpr int KP  = 2*FP + FS;        // 640
    constexpr int KP2 = KP/2;
    __shared__ __align__(16) float As[4*KP];
    __shared__ __align__(16) float smL[2*FS];
    __shared__ __align__(16) float red[512];
    __shared__ float t1L[64];
    const int t  = threadIdx.x;
    if (blockIdx.x >= 256) {             // orb-init + counter-reset (K2 only)
        for (int idx = t; idx < 8192; idx += 512)
            orbInit[idx] = cb[(((idx >> 6) >> 6) << 6) + (idx & 63)];
        if (t == 0)
            __hip_atomic_store(cnt, 0u, __ATOMIC_RELAXED,
                               __HIP_MEMORY_SCOPE_AGENT);
        return;
    }
    const int et = blockIdx.x >> 3;
    const int e0 = et * 4;
    const int o0 = (blockIdx.x & 7) * 64;
    const int ol = t & 63;
    const int o  = o0 + ol;
    const int wv = t >> 6;

    for (int idx = t; idx < 4*2*FP; idx += 512)
        As[(idx/(2*FP))*KP + idx%(2*FP)] =
            pmeIn[(size_t)(e0 + idx/(2*FP))*(2*FP) + idx%(2*FP)];
    for (int idx = t; idx < FS; idx += 512) {
        const int row = idx / (FS/4), c4 = idx % (FS/4);
        *reinterpret_cast<float4*>(&As[row*KP + 2*FP + c4*4]) =
            *reinterpret_cast<const float4*>(&svIn[(size_t)(e0+row)*FS + c4*4]);
    }
    for (int idx = t; idx < 2*FS; idx += 512) {
        const int col = (idx < FS) ? idx : idx - FS;
        const int r0  = (idx < FS) ? 0 : 16;
        const float* base = psumIn + (size_t)r0*NSV + col;
        float s = 0.f;
        #pragma unroll
        for (int k = 0; k < 16; ++k) s += base[(size_t)k*NSV];
        smL[idx] = s * 0.015625f;
    }
    __syncthreads();

    {
        constexpr int TI = (2*FS)/8;
        float a1 = 0.f;
        const float* Wp = Vw + (size_t)(wv*TI)*NSV + o;
        const float* mp = smL + wv*TI;
        #pragma unroll 8
        for (int k = 0; k < TI; ++k) a1 = fmaf(mp[k], Wp[(size_t)k*NSV], a1);
        red[wv*64 + ol] = a1;
    }
    __syncthreads();
    if (t < 64) {
        float s = Vb[o0 + t];
        #pragma unroll
        for (int g = 0; g < 8; ++g) s += red[g*64 + t];
        t1L[t] = s;
    }
    __syncthreads();

    const int e_l = wv & 3, kh = wv >> 2;
    {
        float a2 = (kh == 0) ? t1L[ol] : 0.f;
        const float* Ap = As + e_l*KP + kh*KP2;
        const float* Wp = Vw + (size_t)(2*FS + kh*KP2)*NSV + o;
        #pragma unroll 16
        for (int k = 0; k < KP2; ++k)
            a2 = fmaf(Ap[k], Wp[(size_t)k*NSV], a2);
        red[wv*64 + ol] = a2;
    }
    __syncthreads();
    float v = 0.f;
    if (t < 256) {
        v = tanhf(red[(t>>6)*64 + (t&63)] + red[((t>>6)+4)*64 + (t&63)]);
        svOut[(size_t)(e0 + (t>>6))*NSV + o0 + (t&63)] = v;
    }
    if (psumOut) {
        __syncthreads();
        if (t < 256) red[t] = v;
        __syncthreads();
        if (t < 64) {
            float s = red[t] + red[64+t] + red[128+t] + red[192+t];
            psumOut[(size_t)et*NSV + o0 + t] = s;
        }
    }
}

// ---------------------------------------------------------------------------
// det tail (runs in the LAST a3hd block): two 64x64 log|det| LU.
// orb read via relaxed-agent atomic loads (coherent point — fresh after all
// blocks' vmcnt-drained atomicAdds). expv row scale applied at load.
// ---------------------------------------------------------------------------
__device__ __forceinline__ int imax2(int a, int b) { return a > b ? a : b; }
__device__ __forceinline__ float readlane_f(float x, int lane) {
    return __int_as_float(__builtin_amdgcn_readlane(__float_as_int(x), lane));
}

__device__ void det_tail(const float* __restrict__ orb,
                         const float* __restrict__ expv,
                         float* __restrict__ out, float* shparts)
{
    const int t = threadIdx.x;
    if (t < 128) {
        const int w = t >> 6;
        const int lane = t & 63;
        const float* M = orb + (size_t)w*4096 + (size_t)lane*64;
        const float ex = expv[w*64 + lane];
        float rr[64];
        #pragma unroll
        for (int j = 0; j < 64; j += 2) {
            float2 v = gload2(M + j);
            rr[j] = v.x * ex; rr[j+1] = v.y * ex;
        }
        float pv_mine = 1.f;
        bool active = true;
        #pragma unroll
        for (int k = 0; k < 64; ++k) {
            int bits = (int)(__float_as_uint(rr[k]) & 0x7FFFFFC0u);
            int v = active ? (bits | lane) : lane;
            int tmp;
            tmp = __builtin_amdgcn_update_dpp(0, v, 0xB1,  0xF, 0xF, true); v = imax2(v, tmp);
            tmp = __builtin_amdgcn_update_dpp(0, v, 0x4E,  0xF, 0xF, true); v = imax2(v, tmp);
            tmp = __builtin_amdgcn_update_dpp(0, v, 0x141, 0xF, 0xF, true); v = imax2(v, tmp);
            tmp = __builtin_amdgcn_update_dpp(0, v, 0x140, 0xF, 0xF, true); v = imax2(v, tmp);
            tmp = __builtin_amdgcn_update_dpp(0, v, 0x142, 0xF, 0xF, true); v = imax2(v, tmp);
            tmp = __builtin_amdgcn_update_dpp(0, v, 0x143, 0xF, 0xF, true); v = imax2(v, tmp);
            const int idx = __builtin_amdgcn_readlane(v, 63) & 63;
            const float piv = readlane_f(rr[k], idx);
            pv_mine = (lane == k) ? piv : pv_mine;
            const float linv = __builtin_amdgcn_rcpf(piv);
            const float l = (active && lane != idx) ? rr[k]*linv : 0.f;
            if (lane == idx) active = false;
            #pragma unroll
            for (int j = k+1; j < 64; ++j)
                rr[j] = fmaf(-l, readlane_f(rr[j], idx), rr[j]);
        }
        float lg = logf(fabsf(pv_mine));
        #pragma unroll
        for (int off = 32; off; off >>= 1) lg += __shfl_down(lg, off);
        if (lane == 0) shparts[w] = lg;
    }
    __syncthreads();
    if (t == 0) out[0] = shparts[0] + shparts[1];
}

// ---------------------------------------------------------------------------
// K4: A3 + heads + det. a2 body (afw); svB tile consumed in-block via
// atomic C-partials into orb; the LAST block (relaxed agent counter) runs det.
// ---------------------------------------------------------------------------
__global__ __launch_bounds__(512, 1)
void a3hd_kernel(const float* __restrict__ svIn, const float* __restrict__ pmeIn,
                 const float* __restrict__ psumIn,
                 const float* __restrict__ Vw, const float* __restrict__ Vb,
                 const float* __restrict__ Cmat, float* __restrict__ orb,
                 const float* __restrict__ expv, unsigned* __restrict__ cnt,
                 float* __restrict__ out)
{
    constexpr int FS = 512, FP = 64;
    constexpr int KP  = 2*FP + FS;        // 640
    constexpr int KP2 = KP/2;
    __shared__ __align__(16) float As[4*KP];
    __shared__ __align__(16) float smL[2*FS];
    __shared__ __align__(16) float red[512];
    __shared__ float t1L[64];
    __shared__ unsigned lastrank;
    const int t  = threadIdx.x;
    const int et = blockIdx.x >> 3;
    const int e0 = et * 4;
    const int o0 = (blockIdx.x & 7) * 64;
    const int ol = t & 63;
    const int o  = o0 + ol;
    const int wv = t >> 6;

    for (int idx = t; idx < 4*2*FP; idx += 512)
        As[(idx/(2*FP))*KP + idx%(2*FP)] =
            pmeIn[(size_t)(e0 + idx/(2*FP))*(2*FP) + idx%(2*FP)];
    for (int idx = t; idx < FS; idx += 512) {
        const int row = idx / (FS/4), c4 = idx % (FS/4);
        *reinterpret_cast<float4*>(&As[row*KP + 2*FP + c4*4]) =
            *reinterpret_cast<const float4*>(&svIn[(size_t)(e0+row)*FS + c4*4]);
    }
    for (int idx = t; idx < 2*FS; idx += 512) {
        const int col = (idx < FS) ? idx : idx - FS;
        const int r0  = (idx < FS) ? 0 : 16;
        const float* base = psumIn + (size_t)r0*NSV + col;
        float s = 0.f;
        #pragma unroll
        for (int k = 0; k < 16; ++k) s += base[(size_t)k*NSV];
        smL[idx] = s * 0.015625f;
    }
    __syncthreads();

    {
        constexpr int TI = (2*FS)/8;
        float a1 = 0.f;
        const float* Wp = Vw + (size_t)(wv*TI)*NSV + o;
        const float* mp = smL + wv*TI;
        #pragma unroll 8
        for (int k = 0; k < TI; ++k) a1 = fmaf(mp[k], Wp[(size_t)k*NSV], a1);
        red[wv*64 + ol] = a1;
    }
    __syncthreads();
    if (t < 64) {
        float s = Vb[o0 + t];
        #pragma unroll
        for (int g = 0; g < 8; ++g) s += red[g*64 + t];
        t1L[t] = s;
    }
    __syncthreads();

    const int e_l = wv & 3, kh = wv >> 2;
    {
        float a2 = (kh == 0) ? t1L[ol] : 0.f;
        const float* Ap = As + e_l*KP + kh*KP2;
        const float* Wp = Vw + (size_t)(2*FS + kh*KP2)*NSV + o;
        #pragma unroll 16
        for (int k = 0; k < KP2; ++k)
            a2 = fmaf(Ap[k], Wp[(size_t)k*NSV], a2);
        red[wv*64 + ol] = a2;
    }
    __syncthreads();
    float v = 0.f;
    if (t < 256)
        v = tanhf(red[(t>>6)*64 + (t&63)] + red[((t>>6)+4)*64 + (t&63)]);
    __syncthreads();
    if (t < 256) smL[t] = v;              // svB tile [4e][64f], f = o0+local
    __syncthreads();
    if (t < 256) {
        const int el2 = t >> 6, o2 = t & 63;
        const int spin = et >> 4;
        const float* Cp = Cmat + (size_t)spin*32768 + (size_t)o0*64 + o2;
        const float* sp = smL + el2*64;
        float acc = 0.f;
        #pragma unroll 8
        for (int f = 0; f < 64; ++f)
            acc = fmaf(sp[f], Cp[(size_t)f*64], acc);
        atomicAdd(&orb[(size_t)(e0 + el2)*64 + o2], acc);
    }

    // ---- last-block det: counter increment happens after this block's
    // __syncthreads (vmcnt drained => orb atomics performed at LLC). The
    // block reading old==255 knows all 256 blocks' updates are performed.
    asm volatile("s_waitcnt vmcnt(0)" ::: "memory");
    __syncthreads();
    if (t == 0)
        lastrank = __hip_atomic_fetch_add(cnt, 1u, __ATOMIC_RELAXED,
                                          __HIP_MEMORY_SCOPE_AGENT);
    __syncthreads();
    if (lastrank == 255u)
        det_tail(orb, expv, out, t1L);
}

// ---------------------------------------------------------------------------
extern "C" void kernel_launch(void* const* d_in, const int* in_sizes, int n_in,
                              void* d_out, int out_size, void* d_ws, size_t ws_size,
                              hipStream_t stream)
{
    const float* r    = (const float*)d_in[0];
    const float* apos = (const float*)d_in[1];
    const float* V0w  = (const float*)d_in[2];
    const float* V0b  = (const float*)d_in[3];
    const float* W0w  = (const float*)d_in[4];
    const float* W0b  = (const float*)d_in[5];
    const float* V1w  = (const float*)d_in[6];
    const float* V1b  = (const float*)d_in[7];
    const float* W1w  = (const float*)d_in[8];
    const float* W1b  = (const float*)d_in[9];
    const float* V2w  = (const float*)d_in[10];
    const float* V2b  = (const float*)d_in[11];
    const float* W2w  = (const float*)d_in[12];
    const float* W2b  = (const float*)d_in[13];
    const float* afw  = (const float*)d_in[14];
    const float* afb  = (const float*)d_in[15];
    const float* vhuw = (const float*)d_in[16];
    const float* vhub = (const float*)d_in[17];
    const float* vhdw = (const float*)d_in[18];
    const float* vhdb = (const float*)d_in[19];
    const float* wuw  = (const float*)d_in[20];
    const float* wub  = (const float*)d_in[21];
    const float* wdw  = (const float*)d_in[22];
    const float* wdb  = (const float*)d_in[23];

    float* ws   = (float*)d_ws;
    float* svA  = ws;              // 65536
    float* svB  = svA  + 65536;    // 65536
    float* expv = svB  + 65536;    // 128
    float* pme1 = expv + 128;      // 16384
    float* pme2 = pme1 + 16384;    // 16384
    float* pme3 = pme2 + 16384;    // 16384
    float* psA  = pme3 + 16384;    // 16384
    float* psB  = psA  + 16384;    // 16384
    float* orb  = psB  + 16384;    // 8192
    float* Cmat = orb  + 8192;     // 2*32768
    float* cb   = Cmat + 65536;    // 128
    unsigned* cnt = (unsigned*)(cb + 128);

    // K1: pchain || A0 || headC || cb  (578 independent blocks)
    front_kernel<<<578, 512, 0, stream>>>(r, apos, V0w, V0b, W0w, W0b,
                                          W1w, W1b, W2w, W2b,
                                          vhuw, vhub, vhdw, vhdb,
                                          wuw, wub, wdw, wdb,
                                          svA, expv, pme1, pme2, pme3, psA,
                                          Cmat, cb);
    // K2: A1 (+ orb = cb init and counter reset, block 256)
    a2_kernel<512, 64><<<257, 512, 0, stream>>>(svA, pme1, psA, V1w, V1b,
                                                svB, psB, orb, cb, cnt);
    // K3: A2
    a2_kernel<512, 64><<<256, 512, 0, stream>>>(svB, pme2, psB, V2w, V2b,
                                                svA, psA, nullptr, nullptr, nullptr);
    // K4: A3 + heads + det (last block runs the LU)
    a3hd_kernel<<<256, 512, 0, stream>>>(svA, pme3, psA, afw, afb, Cmat, orb,
                                         expv, cnt, (float*)d_out);
}

// Round 15
// 89.272 us; speedup vs baseline: 1.0628x; 1.0628x over previous
//
#include <hip/hip_runtime.h>
#include <math.h>

#define NSV 512

// ---------------------------------------------------------------------------
// K1 role A (blocks 0..255): pchain split by spin-half (proven R11/R12).
// ---------------------------------------------------------------------------
__device__ void pchain_role(int b, const float* __restrict__ r,
                            const float* __restrict__ apos,
                            const float* __restrict__ W0w, const float* __restrict__ W0b,
                            const float* __restrict__ W1w, const float* __restrict__ W1b,
                            const float* __restrict__ W2w, const float* __restrict__ W2b,
                            float* __restrict__ expv,
                            float* __restrict__ pme1, float* __restrict__ pme2,
                            float* __restrict__ pme3, float* sh)
{
    float* rL    = sh;           // 384
    float* W0l   = sh + 384;     // 256
    float* aposL = sh + 640;     // 96
    float* shex  = sh + 736;     // 32
    float* p0c   = sh + 768;     // 64*4
    float* PA    = sh + 1024;    // 64*68 = 4352
    float* Wbuf  = sh + 5376;    // 4096
    const int j  = b >> 1, sp = b & 1;
    const int t  = threadIdx.x;
    const int i  = t >> 3;          // local row 0..63
    const int o0 = (t & 7) * 8;     // 8 outputs per thread

    if (t < 384) rL[t] = r[t];
    else if (t < 480) aposL[t - 384] = apos[t - 384];
    for (int idx = t; idx < 4096; idx += 512) Wbuf[idx] = W1w[idx];
    if (t < 256) W0l[t] = W0w[t];
    __syncthreads();

    const float rjx = rL[j*3+0], rjy = rL[j*3+1], rjz = rL[j*3+2];
    if (t < 64) {        // p0 rows sp*64+t of column j
        const int ii = sp*64 + t;
        float dx = rjx - rL[ii*3+0], dy = rjy - rL[ii*3+1], dz = rjz - rL[ii*3+2];
        float len = (ii == j) ? 0.f : sqrtf(dx*dx + dy*dy + dz*dz);
        p0c[t*4+0]=dx; p0c[t*4+1]=dy; p0c[t*4+2]=dz; p0c[t*4+3]=len;
    } else if (sp == 0 && t < 96) {   // exp terms for expv[j]
        const int k = t - 64;
        float dx = rjx - aposL[k*3+0], dy = rjy - aposL[k*3+1], dz = rjz - aposL[k*3+2];
        shex[k] = expf(-sqrtf(dx*dx + dy*dy + dz*dz));
    }
    __syncthreads();

    {   // layer0: PA[i][o] = tanh(p0c[i] @ W0 + b0), 8 outputs/thread
        const float x0=p0c[i*4+0], x1=p0c[i*4+1], x2=p0c[i*4+2], x3=p0c[i*4+3];
        #pragma unroll
        for (int k = 0; k < 8; ++k) {
            const int o = o0 + k;
            float a = W0b[o];
            a = fmaf(x0, W0l[o],     a);
            a = fmaf(x1, W0l[64+o],  a);
            a = fmaf(x2, W0l[128+o], a);
            a = fmaf(x3, W0l[192+o], a);
            PA[i*68+o] = tanhf(a);
        }
    }
    if (sp == 0 && t == 4) {
        float s = 0.f;
        #pragma unroll 8
        for (int k = 0; k < 32; ++k) s += shex[k];
        expv[j] = s;
    }
    __syncthreads();

    // pme1 spin-half + layer1 (W1, +res)
    if (t < 64) {
        float s = 0.f;
        #pragma unroll 8
        for (int k = 0; k < 64; ++k) s += PA[k*68 + t];
        pme1[j*128 + sp*64 + t] = s * 0.015625f;
    }
    float acc[8], res[8];
    const float* pa = PA + i*68;
    {
        #pragma unroll
        for (int k = 0; k < 8; ++k) acc[k] = W1b[o0+k];
        #pragma unroll 4
        for (int c = 0; c < 64; ++c) {
            const float av = pa[c];
            const float* wr = Wbuf + c*64 + o0;
            float4 wa = *reinterpret_cast<const float4*>(wr);
            float4 wb = *reinterpret_cast<const float4*>(wr+4);
            acc[0]=fmaf(av,wa.x,acc[0]); acc[1]=fmaf(av,wa.y,acc[1]);
            acc[2]=fmaf(av,wa.z,acc[2]); acc[3]=fmaf(av,wa.w,acc[3]);
            acc[4]=fmaf(av,wb.x,acc[4]); acc[5]=fmaf(av,wb.y,acc[5]);
            acc[6]=fmaf(av,wb.z,acc[6]); acc[7]=fmaf(av,wb.w,acc[7]);
        }
        #pragma unroll
        for (int k = 0; k < 8; ++k) res[k] = pa[o0+k];
    }
    __syncthreads();
    #pragma unroll
    for (int k = 0; k < 8; ++k) PA[i*68+o0+k] = tanhf(acc[k]) + res[k];
    __syncthreads();

    // pme2 spin-half + restage Wbuf = W2
    if (t < 64) {
        float s = 0.f;
        #pragma unroll 8
        for (int k = 0; k < 64; ++k) s += PA[k*68 + t];
        pme2[j*128 + sp*64 + t] = s * 0.015625f;
    }
    for (int idx = t; idx < 4096; idx += 512) Wbuf[idx] = W2w[idx];
    __syncthreads();

    {   // layer2 (W2, +res)
        #pragma unroll
        for (int k = 0; k < 8; ++k) acc[k] = W2b[o0+k];
        #pragma unroll 4
        for (int c = 0; c < 64; ++c) {
            const float av = pa[c];
            const float* wr = Wbuf + c*64 + o0;
            float4 wa = *reinterpret_cast<const float4*>(wr);
            float4 wb = *reinterpret_cast<const float4*>(wr+4);
            acc[0]=fmaf(av,wa.x,acc[0]); acc[1]=fmaf(av,wa.y,acc[1]);
            acc[2]=fmaf(av,wa.z,acc[2]); acc[3]=fmaf(av,wa.w,acc[3]);
            acc[4]=fmaf(av,wb.x,acc[4]); acc[5]=fmaf(av,wb.y,acc[5]);
            acc[6]=fmaf(av,wb.z,acc[6]); acc[7]=fmaf(av,wb.w,acc[7]);
        }
        #pragma unroll
        for (int k = 0; k < 8; ++k) res[k] = pa[o0+k];
    }
    __syncthreads();
    #pragma unroll
    for (int k = 0; k < 8; ++k) PA[i*68+o0+k] = tanhf(acc[k]) + res[k];
    __syncthreads();

    if (t < 64) {        // pme3 spin-half
        float s = 0.f;
        #pragma unroll 8
        for (int k = 0; k < 64; ++k) s += PA[k*68 + t];
        pme3[j*128 + sp*64 + t] = s * 0.015625f;
    }
}

// ---------------------------------------------------------------------------
// K1 role B (blocks 256..511): layer-0 s-GEMM, geometry-sourced (R12-proven).
// ---------------------------------------------------------------------------
__device__ void a0_role(int ab, const float* __restrict__ r,
                        const float* __restrict__ apos,
                        const float* __restrict__ V0w, const float* __restrict__ V0b,
                        float* __restrict__ svA, float* __restrict__ psA, float* sh)
{
    constexpr int KP = 136, KP2 = 68;
    float* As    = sh;           // 544
    float* smL   = sh + 544;     // 256
    float* red   = sh + 800;     // 512
    float* t1L   = sh + 1312;    // 64
    float* rL    = sh + 1376;    // 384
    float* aposL = sh + 1760;    // 96
    const int t  = threadIdx.x;
    const int et = ab >> 3, e0 = et * 4;
    const int o0 = (ab & 7) * 64;
    const int ol = t & 63, o = o0 + ol;
    const int wv = t >> 6;

    if (t < 384) rL[t] = r[t];
    else if (t < 480) aposL[t - 384] = apos[t - 384];
    __syncthreads();

    if (t < 128) {       // As sv-part: 4 electrons x 32 atoms
        const int e_l = t >> 5, k = t & 31;
        const int e = e0 + e_l;
        float dx = rL[e*3+0]-aposL[k*3+0], dy = rL[e*3+1]-aposL[k*3+1],
              dz = rL[e*3+2]-aposL[k*3+2];
        float len = sqrtf(dx*dx + dy*dy + dz*dz);
        float* dst = As + e_l*KP + 8 + k*4;
        dst[0]=dx; dst[1]=dy; dst[2]=dz; dst[3]=len;
    } else if (t < 160) { // As pme0-part: 4 electrons x 8 feats
        const int q = t - 128;
        const int e_l = q >> 3, outp = q & 7;
        const int spin = outp >> 2, c = outp & 3;
        const int e = e0 + e_l;
        const float ex = rL[e*3+0], ey = rL[e*3+1], ez = rL[e*3+2];
        float s = 0.f;
        for (int i2 = 0; i2 < 64; ++i2) {
            const int ii = spin*64 + i2;
            float dx = ex - rL[ii*3+0], dy = ey - rL[ii*3+1], dz = ez - rL[ii*3+2];
            float v = (c==0)?dx:(c==1)?dy:(c==2)?dz:
                      ((ii==e)?0.f:sqrtf(dx*dx+dy*dy+dz*dz));
            s += v;
        }
        As[e_l*KP + outp] = s * 0.015625f;
    }
    {   // smean0 from geometry: two half-sums per thread
        const int outp = t >> 1, half = t & 1;
        const int spin = outp >> 7, cc = outp & 127, a_i = cc >> 2, d = cc & 3;
        const float ax = aposL[a_i*3+0], ay = aposL[a_i*3+1], az = aposL[a_i*3+2];
        float s = 0.f;
        #pragma unroll 8
        for (int q = 0; q < 32; ++q) {
            const int e = spin*64 + half*32 + q;
            float dx = rL[e*3+0]-ax, dy = rL[e*3+1]-ay, dz = rL[e*3+2]-az;
            float len = sqrtf(dx*dx + dy*dy + dz*dz);
            s += (d==0)?dx:(d==1)?dy:(d==2)?dz:len;
        }
        red[t] = s;
    }
    __syncthreads();
    if (t < 256) smL[t] = (red[2*t] + red[2*t+1]) * 0.015625f;
    __syncthreads();

    {   // t1 partials over 8 waves
        float a1 = 0.f;
        const float* Wp = V0w + (size_t)(wv*32)*NSV + o;
        const float* mp = smL + wv*32;
        #pragma unroll 8
        for (int k = 0; k < 32; ++k) a1 = fmaf(mp[k], Wp[(size_t)k*NSV], a1);
        red[wv*64 + ol] = a1;
    }
    __syncthreads();
    if (t < 64) {
        float s = V0b[o0 + t];
        #pragma unroll
        for (int g = 0; g < 8; ++g) s += red[g*64 + t];
        t1L[t] = s;
    }
    __syncthreads();

    const int e_l = wv & 3, kh = wv >> 2;
    {
        float a2 = (kh == 0) ? t1L[ol] : 0.f;
        const float* Ap = As + e_l*KP + kh*KP2;
        const float* Wp = V0w + (size_t)(256 + kh*KP2)*NSV + o;
        #pragma unroll 16
        for (int k = 0; k < KP2; ++k)
            a2 = fmaf(Ap[k], Wp[(size_t)k*NSV], a2);
        red[wv*64 + ol] = a2;
    }
    __syncthreads();
    float v = 0.f;
    if (t < 256) {
        v = tanhf(red[(t>>6)*64 + (t&63)] + red[((t>>6)+4)*64 + (t&63)]);
        svA[(size_t)(e0 + (t>>6))*NSV + o0 + (t&63)] = v;
    }
    __syncthreads();
    if (t < 256) red[t] = v;
    __syncthreads();
    if (t < 64) {
        float s = red[t] + red[64+t] + red[128+t] + red[192+t];
        psA[(size_t)et*NSV + o0 + t] = s;
    }
}

// ---------------------------------------------------------------------------
// K1 role C (blocks 512..575): C = vh @ wu (512x64 per spin), LDS-chunked.
// ---------------------------------------------------------------------------
__device__ void headc_role(int g, const float* __restrict__ vh,
                           const float* __restrict__ wu,
                           float* __restrict__ Cdst, float* sh)
{
    float* wuL = sh;          // 4096
    float* vhL = sh + 4096;   // 1024
    const int t = threadIdx.x;
    const int o2 = t & 63, wq = t >> 6;      // wq 0..7
    const int f0 = g * 16;
    float a0 = 0.f, a1 = 0.f;
    for (int hc = 0; hc < 4; ++hc) {
        __syncthreads();
        for (int idx = t; idx < 4096; idx += 512)
            wuL[idx] = wu[(size_t)(hc*64 + (idx>>6))*64 + (idx&63)];
        for (int idx = t; idx < 1024; idx += 512)
            vhL[idx] = vh[(size_t)(f0 + (idx>>6))*256 + hc*64 + (idx&63)];
        __syncthreads();
        #pragma unroll 8
        for (int h = 0; h < 64; ++h) {
            const float wuv = wuL[h*64 + o2];
            a0 = fmaf(vhL[wq*64 + h],     wuv, a0);
            a1 = fmaf(vhL[(wq+8)*64 + h], wuv, a1);
        }
    }
    Cdst[(size_t)(f0 + wq)*64 + o2]     = a0;
    Cdst[(size_t)(f0 + wq + 8)*64 + o2] = a1;
}

// K1 role D (blocks 576..577): cb = vhb @ wu + wub  (64 per spin).
__device__ void cb_role(const float* __restrict__ vhb, const float* __restrict__ wu,
                        const float* __restrict__ wub, float* __restrict__ cbdst,
                        float* sh)
{
    const int t = threadIdx.x;
    const int o2 = t & 63, wq = t >> 6;
    float acc = 0.f;
    #pragma unroll
    for (int k = 0; k < 32; ++k) {
        const int h = wq*32 + k;
        acc = fmaf(vhb[h], wu[(size_t)h*64 + o2], acc);
    }
    sh[t] = acc;
    __syncthreads();
    if (t < 64) {
        float s = wub[t];
        #pragma unroll
        for (int g = 0; g < 8; ++g) s += sh[g*64 + t];
        cbdst[t] = s;
    }
}

// ---------------------------------------------------------------------------
// K1: pchain(256) || A0(256) || headC(64) || cb(2) — all independent roles.
// ---------------------------------------------------------------------------
__global__ __launch_bounds__(512)
void front_kernel(const float* __restrict__ r, const float* __restrict__ apos,
                  const float* __restrict__ V0w, const float* __restrict__ V0b,
                  const float* __restrict__ W0w, const float* __restrict__ W0b,
                  const float* __restrict__ W1w, const float* __restrict__ W1b,
                  const float* __restrict__ W2w, const float* __restrict__ W2b,
                  const float* __restrict__ vhuw, const float* __restrict__ vhub,
                  const float* __restrict__ vhdw, const float* __restrict__ vhdb,
                  const float* __restrict__ wuw,  const float* __restrict__ wub,
                  const float* __restrict__ wdw,  const float* __restrict__ wdb,
                  float* __restrict__ svA, float* __restrict__ expv,
                  float* __restrict__ pme1, float* __restrict__ pme2,
                  float* __restrict__ pme3, float* __restrict__ psA,
                  float* __restrict__ Cmat, float* __restrict__ cb)
{
    __shared__ __align__(16) float sh[9472];
    const int b = blockIdx.x;
    if (b < 256) {
        pchain_role(b, r, apos, W0w, W0b, W1w, W1b, W2w, W2b,
                    expv, pme1, pme2, pme3, sh);
    } else if (b < 512) {
        a0_role(b - 256, r, apos, V0w, V0b, svA, psA, sh);
    } else if (b < 576) {
        const int g = b - 512;
        const int spin = g >> 5;
        headc_role(g & 31, spin ? vhdw : vhuw, spin ? wdw : wuw,
                   Cmat + (size_t)spin*32768, sh);
    } else {
        const int spin = b - 576;
        cb_role(spin ? vhdb : vhub, spin ? wdw : wuw, spin ? wdb : wub,
                cb + spin*64, sh);
    }
}

// ---------------------------------------------------------------------------
// A kernel (layers 1,2): s-stream GEMM. Grid 256 (+1 for K2: orb=cb init).
// Main K-loop split into 4 independent accumulator chains (dependent-FMA
// latency was the bottleneck at 2 waves/SIMD occupancy).
// ---------------------------------------------------------------------------
template<int FS, int FP>
__global__ __launch_bounds__(512)
void a2_kernel(const float* __restrict__ svIn, const float* __restrict__ pmeIn,
               const float* __restrict__ psumIn,
               const float* __restrict__ Vw, const float* __restrict__ Vb,
               float* __restrict__ svOut, float* __restrict__ psumOut,
               float* __restrict__ orbInit, const float* __restrict__ cb)
{
    constexpr int KP  = 2*FP + FS;        // 640
    constexpr int KP2 = KP/2;
    __shared__ __align__(16) float As[4*KP];
    __shared__ __align__(16) float smL[2*FS];
    __shared__ __align__(16) float red[512];
    __shared__ float t1L[64];
    const int t  = threadIdx.x;
    if (blockIdx.x >= 256) {             // orb-init role (K2 only)
        for (int idx = t; idx < 8192; idx += 512)
            orbInit[idx] = cb[(((idx >> 6) >> 6) << 6) + (idx & 63)];
        return;
    }
    const int et = blockIdx.x >> 3;
    const int e0 = et * 4;
    const int o0 = (blockIdx.x & 7) * 64;
    const int ol = t & 63;
    const int o  = o0 + ol;
    const int wv = t >> 6;

    for (int idx = t; idx < 4*2*FP; idx += 512)
        As[(idx/(2*FP))*KP + idx%(2*FP)] =
            pmeIn[(size_t)(e0 + idx/(2*FP))*(2*FP) + idx%(2*FP)];
    for (int idx = t; idx < FS; idx += 512) {
        const int row = idx / (FS/4), c4 = idx % (FS/4);
        *reinterpret_cast<float4*>(&As[row*KP + 2*FP + c4*4]) =
            *reinterpret_cast<const float4*>(&svIn[(size_t)(e0+row)*FS + c4*4]);
    }
    for (int idx = t; idx < 2*FS; idx += 512) {
        const int col = (idx < FS) ? idx : idx - FS;
        const int r0  = (idx < FS) ? 0 : 16;
        const float* base = psumIn + (size_t)r0*NSV + col;
        float s = 0.f;
        #pragma unroll
        for (int k = 0; k < 16; ++k) s += base[(size_t)k*NSV];
        smL[idx] = s * 0.015625f;
    }
    __syncthreads();

    {   // t1 partials over 8 waves — 4 independent chains
        constexpr int TI = (2*FS)/8;
        const float* Wp = Vw + (size_t)(wv*TI)*NSV + o;
        const float* mp = smL + wv*TI;
        float p0=0.f, p1=0.f, p2=0.f, p3=0.f;
        #pragma unroll 4
        for (int k = 0; k < TI; k += 4) {
            p0 = fmaf(mp[k],   Wp[(size_t)(k  )*NSV], p0);
            p1 = fmaf(mp[k+1], Wp[(size_t)(k+1)*NSV], p1);
            p2 = fmaf(mp[k+2], Wp[(size_t)(k+2)*NSV], p2);
            p3 = fmaf(mp[k+3], Wp[(size_t)(k+3)*NSV], p3);
        }
        red[wv*64 + ol] = (p0 + p1) + (p2 + p3);
    }
    __syncthreads();
    if (t < 64) {
        float s = Vb[o0 + t];
        #pragma unroll
        for (int g = 0; g < 8; ++g) s += red[g*64 + t];
        t1L[t] = s;
    }
    __syncthreads();

    const int e_l = wv & 3, kh = wv >> 2;
    {   // main GEMM, K halves across wave groups — 4 independent chains
        const float* Ap = As + e_l*KP + kh*KP2;
        const float* Wp = Vw + (size_t)(2*FS + kh*KP2)*NSV + o;
        float s0 = (kh == 0) ? t1L[ol] : 0.f;
        float s1=0.f, s2=0.f, s3=0.f;
        #pragma unroll 8
        for (int k = 0; k < KP2; k += 4) {
            s0 = fmaf(Ap[k],   Wp[(size_t)(k  )*NSV], s0);
            s1 = fmaf(Ap[k+1], Wp[(size_t)(k+1)*NSV], s1);
            s2 = fmaf(Ap[k+2], Wp[(size_t)(k+2)*NSV], s2);
            s3 = fmaf(Ap[k+3], Wp[(size_t)(k+3)*NSV], s3);
        }
        red[wv*64 + ol] = (s0 + s1) + (s2 + s3);
    }
    __syncthreads();
    float v = 0.f;
    if (t < 256) {
        v = tanhf(red[(t>>6)*64 + (t&63)] + red[((t>>6)+4)*64 + (t&63)]);
        svOut[(size_t)(e0 + (t>>6))*NSV + o0 + (t&63)] = v;
    }
    if (psumOut) {
        __syncthreads();
        if (t < 256) red[t] = v;
        __syncthreads();
        if (t < 64) {
            float s = red[t] + red[64+t] + red[128+t] + red[192+t];
            psumOut[(size_t)et*NSV + o0 + t] = s;
        }
    }
}

// ---------------------------------------------------------------------------
// K4: A3 + heads fused (R13-proven). Same 4-chain accumulator split.
// ---------------------------------------------------------------------------
__global__ __launch_bounds__(512)
void a3h_kernel(const float* __restrict__ svIn, const float* __restrict__ pmeIn,
                const float* __restrict__ psumIn,
                const float* __restrict__ Vw, const float* __restrict__ Vb,
                const float* __restrict__ Cmat, float* __restrict__ orb)
{
    constexpr int FS = 512, FP = 64;
    constexpr int KP  = 2*FP + FS;        // 640
    constexpr int KP2 = KP/2;
    __shared__ __align__(16) float As[4*KP];
    __shared__ __align__(16) float smL[2*FS];
    __shared__ __align__(16) float red[512];
    __shared__ float t1L[64];
    const int t  = threadIdx.x;
    const int et = blockIdx.x >> 3;
    const int e0 = et * 4;
    const int o0 = (blockIdx.x & 7) * 64;
    const int ol = t & 63;
    const int o  = o0 + ol;
    const int wv = t >> 6;

    for (int idx = t; idx < 4*2*FP; idx += 512)
        As[(idx/(2*FP))*KP + idx%(2*FP)] =
            pmeIn[(size_t)(e0 + idx/(2*FP))*(2*FP) + idx%(2*FP)];
    for (int idx = t; idx < FS; idx += 512) {
        const int row = idx / (FS/4), c4 = idx % (FS/4);
        *reinterpret_cast<float4*>(&As[row*KP + 2*FP + c4*4]) =
            *reinterpret_cast<const float4*>(&svIn[(size_t)(e0+row)*FS + c4*4]);
    }
    for (int idx = t; idx < 2*FS; idx += 512) {
        const int col = (idx < FS) ? idx : idx - FS;
        const int r0  = (idx < FS) ? 0 : 16;
        const float* base = psumIn + (size_t)r0*NSV + col;
        float s = 0.f;
        #pragma unroll
        for (int k = 0; k < 16; ++k) s += base[(size_t)k*NSV];
        smL[idx] = s * 0.015625f;
    }
    __syncthreads();

    {   // t1 partials — 4 chains
        constexpr int TI = (2*FS)/8;
        const float* Wp = Vw + (size_t)(wv*TI)*NSV + o;
        const float* mp = smL + wv*TI;
        float p0=0.f, p1=0.f, p2=0.f, p3=0.f;
        #pragma unroll 4
        for (int k = 0; k < TI; k += 4) {
            p0 = fmaf(mp[k],   Wp[(size_t)(k  )*NSV], p0);
            p1 = fmaf(mp[k+1], Wp[(size_t)(k+1)*NSV], p1);
            p2 = fmaf(mp[k+2], Wp[(size_t)(k+2)*NSV], p2);
            p3 = fmaf(mp[k+3], Wp[(size_t)(k+3)*NSV], p3);
        }
        red[wv*64 + ol] = (p0 + p1) + (p2 + p3);
    }
    __syncthreads();
    if (t < 64) {
        float s = Vb[o0 + t];
        #pragma unroll
        for (int g = 0; g < 8; ++g) s += red[g*64 + t];
        t1L[t] = s;
    }
    __syncthreads();

    const int e_l = wv & 3, kh = wv >> 2;
    {   // main GEMM — 4 chains
        const float* Ap = As + e_l*KP + kh*KP2;
        const float* Wp = Vw + (size_t)(2*FS + kh*KP2)*NSV + o;
        float s0 = (kh == 0) ? t1L[ol] : 0.f;
        float s1=0.f, s2=0.f, s3=0.f;
        #pragma unroll 8
        for (int k = 0; k < KP2; k += 4) {
            s0 = fmaf(Ap[k],   Wp[(size_t)(k  )*NSV], s0);
            s1 = fmaf(Ap[k+1], Wp[(size_t)(k+1)*NSV], s1);
            s2 = fmaf(Ap[k+2], Wp[(size_t)(k+2)*NSV], s2);
            s3 = fmaf(Ap[k+3], Wp[(size_t)(k+3)*NSV], s3);
        }
        red[wv*64 + ol] = (s0 + s1) + (s2 + s3);
    }
    __syncthreads();
    float v = 0.f;
    if (t < 256)
        v = tanhf(red[(t>>6)*64 + (t&63)] + red[((t>>6)+4)*64 + (t&63)]);
    __syncthreads();
    if (t < 256) smL[t] = v;              // svB tile [4e][64f], f = o0+local
    __syncthreads();
    if (t < 256) {
        const int el2 = t >> 6, o2 = t & 63;
        const int spin = et >> 4;
        const float* Cp = Cmat + (size_t)spin*32768 + (size_t)o0*64 + o2;
        const float* sp = smL + el2*64;
        float acc = 0.f;
        #pragma unroll 8
        for (int f = 0; f < 64; ++f)
            acc = fmaf(sp[f], Cp[(size_t)f*64], acc);
        atomicAdd(&orb[(size_t)(e0 + el2)*64 + o2], acc);
    }
}

// ---------------------------------------------------------------------------
// det: two 64x64 log|det| LU; expv row-scale applied at load. Own dispatch
// (R14 lesson: fused with a GEMM body, regalloc spills rr[64] -> 55us).
// ---------------------------------------------------------------------------
__device__ __forceinline__ int imax2(int a, int b) { return a > b ? a : b; }
__device__ __forceinline__ float readlane_f(float x, int lane) {
    return __int_as_float(__builtin_amdgcn_readlane(__float_as_int(x), lane));
}

__global__ __launch_bounds__(128)
void det_kernel(const float* __restrict__ orb, const float* __restrict__ expv,
                float* __restrict__ out)
{
    __shared__ float parts[2];
    const int t = threadIdx.x;
    const int w = t >> 6;
    const int lane = t & 63;
    const float* M = orb + (size_t)w*4096 + (size_t)lane*64;
    const float ex = expv[w*64 + lane];
    float rr[64];
    #pragma unroll
    for (int j = 0; j < 64; j += 4) {
        float4 v = *reinterpret_cast<const float4*>(M + j);
        rr[j]=v.x*ex; rr[j+1]=v.y*ex; rr[j+2]=v.z*ex; rr[j+3]=v.w*ex;
    }
    float pv_mine = 1.f;
    bool active = true;
    #pragma unroll
    for (int k = 0; k < 64; ++k) {
        int bits = (int)(__float_as_uint(rr[k]) & 0x7FFFFFC0u);
        int v = active ? (bits | lane) : lane;
        int tmp;
        tmp = __builtin_amdgcn_update_dpp(0, v, 0xB1,  0xF, 0xF, true); v = imax2(v, tmp);
        tmp = __builtin_amdgcn_update_dpp(0, v, 0x4E,  0xF, 0xF, true); v = imax2(v, tmp);
        tmp = __builtin_amdgcn_update_dpp(0, v, 0x141, 0xF, 0xF, true); v = imax2(v, tmp);
        tmp = __builtin_amdgcn_update_dpp(0, v, 0x140, 0xF, 0xF, true); v = imax2(v, tmp);
        tmp = __builtin_amdgcn_update_dpp(0, v, 0x142, 0xF, 0xF, true); v = imax2(v, tmp);
        tmp = __builtin_amdgcn_update_dpp(0, v, 0x143, 0xF, 0xF, true); v = imax2(v, tmp);
        const int idx = __builtin_amdgcn_readlane(v, 63) & 63;
        const float piv = readlane_f(rr[k], idx);
        pv_mine = (lane == k) ? piv : pv_mine;
        const float linv = __builtin_amdgcn_rcpf(piv);
        const float l = (active && lane != idx) ? rr[k]*linv : 0.f;
        if (lane == idx) active = false;
        #pragma unroll
        for (int j = k+1; j < 64; ++j)
            rr[j] = fmaf(-l, readlane_f(rr[j], idx), rr[j]);
    }
    float lg = logf(fabsf(pv_mine));
    #pragma unroll
    for (int off = 32; off; off >>= 1) lg += __shfl_down(lg, off);
    if (lane == 0) parts[w] = lg;
    __syncthreads();
    if (t == 0) out[0] = parts[0] + parts[1];
}

// ---------------------------------------------------------------------------
extern "C" void kernel_launch(void* const* d_in, const int* in_sizes, int n_in,
                              void* d_out, int out_size, void* d_ws, size_t ws_size,
                              hipStream_t stream)
{
    const float* r    = (const float*)d_in[0];
    const float* apos = (const float*)d_in[1];
    const float* V0w  = (const float*)d_in[2];
    const float* V0b  = (const float*)d_in[3];
    const float* W0w  = (const float*)d_in[4];
    const float* W0b  = (const float*)d_in[5];
    const float* V1w  = (const float*)d_in[6];
    const float* V1b  = (const float*)d_in[7];
    const float* W1w  = (const float*)d_in[8];
    const float* W1b  = (const float*)d_in[9];
    const float* V2w  = (const float*)d_in[10];
    const float* V2b  = (const float*)d_in[11];
    const float* W2w  = (const float*)d_in[12];
    const float* W2b  = (const float*)d_in[13];
    const float* afw  = (const float*)d_in[14];
    const float* afb  = (const float*)d_in[15];
    const float* vhuw = (const float*)d_in[16];
    const float* vhub = (const float*)d_in[17];
    const float* vhdw = (const float*)d_in[18];
    const float* vhdb = (const float*)d_in[19];
    const float* wuw  = (const float*)d_in[20];
    const float* wub  = (const float*)d_in[21];
    const float* wdw  = (const float*)d_in[22];
    const float* wdb  = (const float*)d_in[23];

    float* ws   = (float*)d_ws;
    float* svA  = ws;              // 65536
    float* svB  = svA  + 65536;    // 65536
    float* expv = svB  + 65536;    // 128
    float* pme1 = expv + 128;      // 16384
    float* pme2 = pme1 + 16384;    // 16384
    float* pme3 = pme2 + 16384;    // 16384
    float* psA  = pme3 + 16384;    // 16384
    float* psB  = psA  + 16384;    // 16384
    float* orb  = psB  + 16384;    // 8192
    float* Cmat = orb  + 8192;     // 2*32768
    float* cb   = Cmat + 65536;    // 128

    // K1: pchain || A0 || headC || cb  (578 independent blocks)
    front_kernel<<<578, 512, 0, stream>>>(r, apos, V0w, V0b, W0w, W0b,
                                          W1w, W1b, W2w, W2b,
                                          vhuw, vhub, vhdw, vhdb,
                                          wuw, wub, wdw, wdb,
                                          svA, expv, pme1, pme2, pme3, psA,
                                          Cmat, cb);
    // K2: A1 (+ orb = cb init role, block 256)
    a2_kernel<512, 64><<<257, 512, 0, stream>>>(svA, pme1, psA, V1w, V1b,
                                                svB, psB, orb, cb);
    // K3: A2
    a2_kernel<512, 64><<<256, 512, 0, stream>>>(svB, pme2, psB, V2w, V2b,
                                                svA, psA, nullptr, nullptr);
    // K4: A3 + heads (atomic C-partials into orb; svB never stored)
    a3h_kernel<<<256, 512, 0, stream>>>(svA, pme3, psA, afw, afb, Cmat, orb);
    // K5: determinants (applies expv row scale)
    det_kernel<<<1, 128, 0, stream>>>(orb, expv, (float*)d_out);
}